// Round 2
// baseline (683.580 us; speedup 1.0000x reference)
//
#include <hip/hip_runtime.h>
#include <hip/hip_bf16.h>

// MHA forward: B=4, T=2048, N=1024, H=16, Dh=64.
// Round 2: transposed flash attention (S^T = K Q^T, O^T = V^T P^T) so softmax
// reduces in-lane (2 shuffles per 64-key tile instead of 64), 64-key tiles,
// reversed block order for causal load balance.

typedef __attribute__((ext_vector_type(8))) short short8;   // 8 x bf16 (4 VGPR)
typedef __attribute__((ext_vector_type(4))) float f32x4;

#define MFMA16(a, b, c) __builtin_amdgcn_mfma_f32_16x16x32_bf16((a), (b), (c), 0, 0, 0)

__device__ inline unsigned short f2bfu(float f) {
  union { __hip_bfloat16 h; unsigned short u; } cv;
  cv.h = __float2bfloat16(f);
  return cv.u;
}

// ---------------- elementwise fp32 -> bf16 ----------------
__global__ void conv_f32_bf16(const float* __restrict__ src,
                              unsigned short* __restrict__ dst, int n4) {
  int i = blockIdx.x * blockDim.x + threadIdx.x;
  if (i >= n4) return;
  float4 v = ((const float4*)src)[i];
  ushort4 o;
  o.x = f2bfu(v.x); o.y = f2bfu(v.y); o.z = f2bfu(v.z); o.w = f2bfu(v.w);
  ((ushort4*)dst)[i] = o;
}

// ---------------- transpose + convert: dst[c][r] = bf16(src[r][c]) ----------------
__global__ void transpose_bf16(const float* __restrict__ src,
                               __hip_bfloat16* __restrict__ dst, int R, int C) {
  __shared__ float tile[32][33];
  int tx = threadIdx.x, ty = threadIdx.y;          // block (32, 8)
  int c0 = blockIdx.x * 32, r0 = blockIdx.y * 32;
#pragma unroll
  for (int i = 0; i < 32; i += 8)
    tile[ty + i][tx] = src[(long)(r0 + ty + i) * C + c0 + tx];
  __syncthreads();
#pragma unroll
  for (int i = 0; i < 32; i += 8)
    dst[(long)(c0 + ty + i) * R + r0 + tx] = __float2bfloat16(tile[tx][ty + i]);
}

// ---------------- GEMM: C[M,N] = A[M,K] @ Bt[N,K]^T + bias ----------------
// EPI=0: scatter bf16 into Q[B,H,T,Dh], K[B,H,T,Dh], Vt[B,H,Dh,T]
// EPI=1: write fp32 to out
template <int EPI>
__global__ __launch_bounds__(256, 2) void gemm_bt(
    const __hip_bfloat16* __restrict__ A, const __hip_bfloat16* __restrict__ Bt,
    const float* __restrict__ bias, void* o0, void* o1, void* o2, int N, int K) {
  __shared__ short8 As[128][8];
  __shared__ short8 Bs[128][8];
  const int tid = threadIdx.x;
  const int lane = tid & 63, w = tid >> 6;
  const int l15 = lane & 15, quad = lane >> 4;
  const int wm = (w >> 1) * 64, wn = (w & 1) * 64;   // wave sub-tile origin in 128x128
  const int rowBase = blockIdx.y * 128;
  const int colBase = blockIdx.x * 128;
  const int srow = tid >> 3, schunk = tid & 7;       // staging: 8 chunks per row

  f32x4 acc[4][4];
#pragma unroll
  for (int mi = 0; mi < 4; ++mi)
#pragma unroll
    for (int ni = 0; ni < 4; ++ni)
      acc[mi][ni] = {0.f, 0.f, 0.f, 0.f};

  for (int k0 = 0; k0 < K; k0 += 64) {
    __syncthreads();
#pragma unroll
    for (int p = 0; p < 4; ++p) {
      int row = p * 32 + srow;
      As[row][schunk ^ (row & 7)] =
          *(const short8*)(A + (rowBase + row) * K + k0 + schunk * 8);
      Bs[row][schunk ^ (row & 7)] =
          *(const short8*)(Bt + (colBase + row) * K + k0 + schunk * 8);
    }
    __syncthreads();
#pragma unroll
    for (int kc = 0; kc < 2; ++kc) {
      short8 af[4], bf[4];
#pragma unroll
      for (int mi = 0; mi < 4; ++mi) {
        int row = wm + mi * 16 + l15;
        af[mi] = As[row][(kc * 4 + quad) ^ (row & 7)];
      }
#pragma unroll
      for (int ni = 0; ni < 4; ++ni) {
        int row = wn + ni * 16 + l15;
        bf[ni] = Bs[row][(kc * 4 + quad) ^ (row & 7)];
      }
#pragma unroll
      for (int mi = 0; mi < 4; ++mi)
#pragma unroll
        for (int ni = 0; ni < 4; ++ni)
          acc[mi][ni] = MFMA16(af[mi], bf[ni], acc[mi][ni]);
    }
  }

  // epilogue
#pragma unroll
  for (int mi = 0; mi < 4; ++mi) {
#pragma unroll
    for (int ni = 0; ni < 4; ++ni) {
#pragma unroll
      for (int r = 0; r < 4; ++r) {
        int grow = rowBase + wm + mi * 16 + quad * 4 + r;
        int gcol = colBase + wn + ni * 16 + l15;
        float v = acc[mi][ni][r] + bias[gcol];
        if (EPI == 0) {
          __hip_bfloat16 bv = __float2bfloat16(v);
          int b = grow >> 11, t = grow & 2047;          // T = 2048
          int which = gcol >> 10, n1 = gcol & 1023;     // N = 1024
          int h = n1 >> 6, d = n1 & 63;                 // Dh = 64
          int bh = b * 16 + h;
          if (which == 0)
            ((__hip_bfloat16*)o0)[(bh * 2048 + t) * 64 + d] = bv;       // Q[B,H,T,Dh]
          else if (which == 1)
            ((__hip_bfloat16*)o1)[(bh * 2048 + t) * 64 + d] = bv;       // K[B,H,T,Dh]
          else
            ((__hip_bfloat16*)o2)[(bh * 64 + d) * 2048 + t] = bv;       // Vt[B,H,Dh,T]
        } else {
          ((float*)o0)[(long)grow * N + gcol] = v;
        }
      }
    }
  }
}

// ---------------- transposed flash attention ----------------
// One wave = 16 q rows; 64-key tiles. S^T = K.Q^T: C-layout row=key(quad*4+r),
// col=q(l15) -> each q column lives in lanes with the same l15 => softmax max/sum
// reduce in-lane over 16 regs + shfl_xor(16) + shfl_xor(32) only.
// O^T = V^T.P^T accumulates with col=q(l15): alpha rescale is lane-uniform.
__global__ __launch_bounds__(256) void attn_kernel(
    const __hip_bfloat16* __restrict__ Q, const __hip_bfloat16* __restrict__ K,
    const __hip_bfloat16* __restrict__ Vt, __hip_bfloat16* __restrict__ Y, int T) {
  __shared__ alignas(16) unsigned short Pl[4][16][72];  // per-wave P[q][key], pad 72
  const int tid = threadIdx.x;
  const int w = tid >> 6, lane = tid & 63, l15 = lane & 15, quad = lane >> 4;
  const int bh = blockIdx.y;                 // b*16 + h
  const int b = bh >> 4, h = bh & 15;
  const int qb = gridDim.x - 1 - blockIdx.x; // reversed: heavy blocks dispatch first
  const int qrow0 = qb * 64 + w * 16;
  const __hip_bfloat16* Qp = Q + (long)bh * T * 64;
  const __hip_bfloat16* Kp = K + (long)bh * T * 64;
  const __hip_bfloat16* Vp = Vt + (long)bh * 64 * T;

  // Q as B-fragments of Q^T: B[k=quad*8+j][n=l15] = Q[qrow0+l15][quad*8+j]
  short8 q0 = *(const short8*)(Qp + (qrow0 + l15) * 64 + quad * 8);
  short8 q1 = *(const short8*)(Qp + (qrow0 + l15) * 64 + 32 + quad * 8);

  f32x4 oacc[4];
#pragma unroll
  for (int g = 0; g < 4; ++g) oacc[g] = {0.f, 0.f, 0.f, 0.f};
  float m = -INFINITY, l = 0.f;
  const float cscale = 0.125f * 1.44269504089f;  // 1/sqrt(64) * log2(e)
  const int myq = qrow0 + l15;
  const int nkt = qb + 1;                        // all 4 waves: same trip count

  for (int kt = 0; kt < nkt; ++kt) {
    const int kb = kt * 64;
    // S^T tile: 64 keys x 16 q, frag g covers keys kb+g*16..+15
    f32x4 st[4];
#pragma unroll
    for (int g = 0; g < 4; ++g) {
      short8 k0 = *(const short8*)(Kp + (kb + g * 16 + l15) * 64 + quad * 8);
      short8 k1 = *(const short8*)(Kp + (kb + g * 16 + l15) * 64 + 32 + quad * 8);
      f32x4 z = {0.f, 0.f, 0.f, 0.f};
      z = MFMA16(k0, q0, z);
      z = MFMA16(k1, q1, z);
      st[g] = z;
    }
    // mask + scale; per-lane 16 vals all belong to q=myq
    float a[16];
    float tmax = -INFINITY;
#pragma unroll
    for (int g = 0; g < 4; ++g)
#pragma unroll
      for (int r = 0; r < 4; ++r) {
        int key = kb + g * 16 + quad * 4 + r;
        float v = (key <= myq) ? st[g][r] * cscale : -INFINITY;
        a[g * 4 + r] = v;
        tmax = fmaxf(tmax, v);
      }
    tmax = fmaxf(tmax, __shfl_xor(tmax, 16));
    tmax = fmaxf(tmax, __shfl_xor(tmax, 32));
    const float mnew = fmaxf(m, tmax);           // finite: key kb is unmasked
    const float alpha = exp2f(m - mnew);
    m = mnew;
    float rs = 0.f;
#pragma unroll
    for (int g = 0; g < 4; ++g) {
      ushort4 pk;
      float p0 = exp2f(a[g * 4 + 0] - mnew);
      float p1 = exp2f(a[g * 4 + 1] - mnew);
      float p2 = exp2f(a[g * 4 + 2] - mnew);
      float p3 = exp2f(a[g * 4 + 3] - mnew);
      rs += (p0 + p1) + (p2 + p3);
      pk.x = f2bfu(p0); pk.y = f2bfu(p1); pk.z = f2bfu(p2); pk.w = f2bfu(p3);
      // P[q=l15][key local g*16+quad*4 .. +3]
      *(ushort4*)&Pl[w][l15][g * 16 + quad * 4] = pk;
    }
    rs += __shfl_xor(rs, 16);
    rs += __shfl_xor(rs, 32);
    l = l * alpha + rs;
#pragma unroll
    for (int g = 0; g < 4; ++g)
#pragma unroll
      for (int r = 0; r < 4; ++r) oacc[g][r] *= alpha;
    // P^T B-frags: B[k=quad*8+j][n=l15] = P[l15][s*32+quad*8+j]
    short8 pb0 = *(short8*)&Pl[w][l15][quad * 8];
    short8 pb1 = *(short8*)&Pl[w][l15][32 + quad * 8];
    // O^T += V^T.P^T ; A-frag: V^T[d=g*16+l15][key=kb+s*32+quad*8+j]
#pragma unroll
    for (int g = 0; g < 4; ++g) {
      short8 v0 = *(const short8*)(Vp + (g * 16 + l15) * (long)T + kb + quad * 8);
      short8 v1 = *(const short8*)(Vp + (g * 16 + l15) * (long)T + kb + 32 + quad * 8);
      oacc[g] = MFMA16(v0, pb0, oacc[g]);
      oacc[g] = MFMA16(v1, pb1, oacc[g]);
    }
  }

  // O^T[d=g*16+quad*4+r][q=l15] -> Y[b*2048+qrow0+l15][h*64 + d]
  const float inv = 1.0f / l;
  unsigned short* Yu = (unsigned short*)Y;
  const long rowoff = ((long)(b * 2048 + qrow0 + l15)) * 1024 + h * 64;
#pragma unroll
  for (int g = 0; g < 4; ++g) {
    ushort4 o;
    o.x = f2bfu(oacc[g][0] * inv);
    o.y = f2bfu(oacc[g][1] * inv);
    o.z = f2bfu(oacc[g][2] * inv);
    o.w = f2bfu(oacc[g][3] * inv);
    *(ushort4*)&Yu[rowoff + g * 16 + quad * 4] = o;
  }
}

extern "C" void kernel_launch(void* const* d_in, const int* in_sizes, int n_in,
                              void* d_out, int out_size, void* d_ws, size_t ws_size,
                              hipStream_t stream) {
  const float* x  = (const float*)d_in[0];   // [4,2048,1024]
  const float* Wa = (const float*)d_in[1];   // [1024,3072]
  const float* ba = (const float*)d_in[2];   // [3072]
  const float* Wp = (const float*)d_in[3];   // [1024,1024]
  const float* bp = (const float*)d_in[4];   // [1024]
  float* out = (float*)d_out;                // [4,2048,1024] fp32

  char* ws = (char*)d_ws;
  __hip_bfloat16* Xb  = (__hip_bfloat16*)(ws);              // [8192,1024]
  __hip_bfloat16* WaT = (__hip_bfloat16*)(ws + 16777216);   // [3072,1024]
  __hip_bfloat16* WpT = (__hip_bfloat16*)(ws + 23068672);   // [1024,1024]
  __hip_bfloat16* Qb  = (__hip_bfloat16*)(ws + 25165824);   // [B,H,T,Dh]
  __hip_bfloat16* Kb  = (__hip_bfloat16*)(ws + 41943040);   // [B,H,T,Dh]
  __hip_bfloat16* Vtb = (__hip_bfloat16*)(ws + 58720256);   // [B,H,Dh,T]
  __hip_bfloat16* Yb  = (__hip_bfloat16*)(ws + 75497472);   // [8192,1024]
  if (ws_size < 92274688) return;

  conv_f32_bf16<<<8192, 256, 0, stream>>>(x, (unsigned short*)Xb, 2097152);
  transpose_bf16<<<dim3(96, 32), dim3(32, 8), 0, stream>>>(Wa, WaT, 1024, 3072);
  transpose_bf16<<<dim3(32, 32), dim3(32, 8), 0, stream>>>(Wp, WpT, 1024, 1024);
  gemm_bt<0><<<dim3(24, 64), 256, 0, stream>>>(Xb, WaT, ba, Qb, Kb, Vtb, 3072, 1024);
  attn_kernel<<<dim3(32, 64), 256, 0, stream>>>(Qb, Kb, Vtb, Yb, 2048);
  gemm_bt<1><<<dim3(8, 64), 256, 0, stream>>>(Yb, WpT, bp, out, nullptr, nullptr, 1024, 1024);
}

// Round 3
// 373.839 us; speedup vs baseline: 1.8285x; 1.8285x over previous
//
#include <hip/hip_runtime.h>
#include <hip/hip_bf16.h>

// MHA forward: B=4, T=2048, N=1024, H=16, Dh=64.
// Round 3: flash attention with block-shared, double-buffered LDS K/V tiles
// (prefetch regs -> compute -> ds_write -> one barrier per tile). Softmax stays
// in-lane (transposed S^T = K.Q^T scheme from round 2).

typedef __attribute__((ext_vector_type(8))) short short8;   // 8 x bf16 (4 VGPR)
typedef __attribute__((ext_vector_type(4))) float f32x4;

#define MFMA16(a, b, c) __builtin_amdgcn_mfma_f32_16x16x32_bf16((a), (b), (c), 0, 0, 0)

__device__ inline unsigned short f2bfu(float f) {
  union { __hip_bfloat16 h; unsigned short u; } cv;
  cv.h = __float2bfloat16(f);
  return cv.u;
}

// ---------------- elementwise fp32 -> bf16 ----------------
__global__ void conv_f32_bf16(const float* __restrict__ src,
                              unsigned short* __restrict__ dst, int n4) {
  int i = blockIdx.x * blockDim.x + threadIdx.x;
  if (i >= n4) return;
  float4 v = ((const float4*)src)[i];
  ushort4 o;
  o.x = f2bfu(v.x); o.y = f2bfu(v.y); o.z = f2bfu(v.z); o.w = f2bfu(v.w);
  ((ushort4*)dst)[i] = o;
}

// ---------------- transpose + convert: dst[c][r] = bf16(src[r][c]) ----------------
__global__ void transpose_bf16(const float* __restrict__ src,
                               __hip_bfloat16* __restrict__ dst, int R, int C) {
  __shared__ float tile[32][33];
  int tx = threadIdx.x, ty = threadIdx.y;          // block (32, 8)
  int c0 = blockIdx.x * 32, r0 = blockIdx.y * 32;
#pragma unroll
  for (int i = 0; i < 32; i += 8)
    tile[ty + i][tx] = src[(long)(r0 + ty + i) * C + c0 + tx];
  __syncthreads();
#pragma unroll
  for (int i = 0; i < 32; i += 8)
    dst[(long)(c0 + ty + i) * R + r0 + tx] = __float2bfloat16(tile[tx][ty + i]);
}

// ---------------- GEMM: C[M,N] = A[M,K] @ Bt[N,K]^T + bias ----------------
template <int EPI>
__global__ __launch_bounds__(256, 2) void gemm_bt(
    const __hip_bfloat16* __restrict__ A, const __hip_bfloat16* __restrict__ Bt,
    const float* __restrict__ bias, void* o0, void* o1, void* o2, int N, int K) {
  __shared__ short8 As[128][8];
  __shared__ short8 Bs[128][8];
  const int tid = threadIdx.x;
  const int lane = tid & 63, w = tid >> 6;
  const int l15 = lane & 15, quad = lane >> 4;
  const int wm = (w >> 1) * 64, wn = (w & 1) * 64;
  const int rowBase = blockIdx.y * 128;
  const int colBase = blockIdx.x * 128;
  const int srow = tid >> 3, schunk = tid & 7;

  f32x4 acc[4][4];
#pragma unroll
  for (int mi = 0; mi < 4; ++mi)
#pragma unroll
    for (int ni = 0; ni < 4; ++ni)
      acc[mi][ni] = {0.f, 0.f, 0.f, 0.f};

  for (int k0 = 0; k0 < K; k0 += 64) {
    __syncthreads();
#pragma unroll
    for (int p = 0; p < 4; ++p) {
      int row = p * 32 + srow;
      As[row][schunk ^ (row & 7)] =
          *(const short8*)(A + (rowBase + row) * K + k0 + schunk * 8);
      Bs[row][schunk ^ (row & 7)] =
          *(const short8*)(Bt + (colBase + row) * K + k0 + schunk * 8);
    }
    __syncthreads();
#pragma unroll
    for (int kc = 0; kc < 2; ++kc) {
      short8 af[4], bf[4];
#pragma unroll
      for (int mi = 0; mi < 4; ++mi) {
        int row = wm + mi * 16 + l15;
        af[mi] = As[row][(kc * 4 + quad) ^ (row & 7)];
      }
#pragma unroll
      for (int ni = 0; ni < 4; ++ni) {
        int row = wn + ni * 16 + l15;
        bf[ni] = Bs[row][(kc * 4 + quad) ^ (row & 7)];
      }
#pragma unroll
      for (int mi = 0; mi < 4; ++mi)
#pragma unroll
        for (int ni = 0; ni < 4; ++ni)
          acc[mi][ni] = MFMA16(af[mi], bf[ni], acc[mi][ni]);
    }
  }

#pragma unroll
  for (int mi = 0; mi < 4; ++mi) {
#pragma unroll
    for (int ni = 0; ni < 4; ++ni) {
#pragma unroll
      for (int r = 0; r < 4; ++r) {
        int grow = rowBase + wm + mi * 16 + quad * 4 + r;
        int gcol = colBase + wn + ni * 16 + l15;
        float v = acc[mi][ni][r] + bias[gcol];
        if (EPI == 0) {
          __hip_bfloat16 bv = __float2bfloat16(v);
          int b = grow >> 11, t = grow & 2047;          // T = 2048
          int which = gcol >> 10, n1 = gcol & 1023;     // N = 1024
          int h = n1 >> 6, d = n1 & 63;                 // Dh = 64
          int bh = b * 16 + h;
          if (which == 0)
            ((__hip_bfloat16*)o0)[(bh * 2048 + t) * 64 + d] = bv;       // Q[B,H,T,Dh]
          else if (which == 1)
            ((__hip_bfloat16*)o1)[(bh * 2048 + t) * 64 + d] = bv;       // K[B,H,T,Dh]
          else
            ((__hip_bfloat16*)o2)[(bh * 64 + d) * 2048 + t] = bv;       // Vt[B,H,Dh,T]
        } else {
          ((float*)o0)[(long)grow * N + gcol] = v;
        }
      }
    }
  }
}

// ---------------- flash attention, block-shared double-buffered K/V ----------------
// Block = 64 q rows (4 waves x 16 q), iterates 64-key tiles 0..qb.
// S^T = K.Q^T (C-layout: row=key, col=q) -> softmax reduces in-lane + 2 shuffles.
// O^T = V^T.P^T, P round-trips per-wave LDS (verified transform).
__global__ __launch_bounds__(256) void attn_kernel(
    const __hip_bfloat16* __restrict__ Q, const __hip_bfloat16* __restrict__ K,
    const __hip_bfloat16* __restrict__ Vt, __hip_bfloat16* __restrict__ Y, int T) {
  __shared__ short8 Ks[2][64][8];                       // [buf][key][chunk^  (key&7)]
  __shared__ short8 Vs[2][64][8];                       // [buf][dim][chunk^  (dim&7)]
  __shared__ alignas(16) unsigned short Pl[4][16][72];  // per-wave P[q][key]
  const int tid = threadIdx.x;
  const int w = tid >> 6, lane = tid & 63, l15 = lane & 15, quad = lane >> 4;
  const int bh = blockIdx.y;                 // b*16 + h
  const int b = bh >> 4, h = bh & 15;
  const int qb = gridDim.x - 1 - blockIdx.x; // heavy blocks dispatch first
  const int qrow0 = qb * 64 + w * 16;
  const __hip_bfloat16* Qp = Q + (long)bh * T * 64;
  const __hip_bfloat16* Kp = K + (long)bh * T * 64;
  const __hip_bfloat16* Vp = Vt + (long)bh * 64 * T;

  // staging role: thread -> (row sr, chunk sc) and (row sr+32, chunk sc)
  const int sr = tid >> 3, sc = tid & 7;

  // Q as B-fragments of Q^T
  short8 q0 = *(const short8*)(Qp + (qrow0 + l15) * 64 + quad * 8);
  short8 q1 = *(const short8*)(Qp + (qrow0 + l15) * 64 + 32 + quad * 8);

  f32x4 oacc[4];
#pragma unroll
  for (int g = 0; g < 4; ++g) oacc[g] = {0.f, 0.f, 0.f, 0.f};
  float m = -INFINITY, l = 0.f;
  const float cscale = 0.125f * 1.44269504089f;  // 1/sqrt(64) * log2(e)
  const int myq = qrow0 + l15;
  const int nkt = qb + 1;                        // uniform across waves -> barriers safe
  const int rsw = l15 & 7;                       // frag-read row swizzle

  // prologue: stage tile 0
  {
    short8 ka0 = *(const short8*)(Kp + sr * 64 + sc * 8);
    short8 ka1 = *(const short8*)(Kp + (sr + 32) * 64 + sc * 8);
    short8 va0 = *(const short8*)(Vp + (long)sr * T + sc * 8);
    short8 va1 = *(const short8*)(Vp + (long)(sr + 32) * T + sc * 8);
    Ks[0][sr][sc ^ (sr & 7)] = ka0;
    Ks[0][sr + 32][sc ^ (sr & 7)] = ka1;
    Vs[0][sr][sc ^ (sr & 7)] = va0;
    Vs[0][sr + 32][sc ^ (sr & 7)] = va1;
  }
  __syncthreads();

  for (int kt = 0; kt < nkt; ++kt) {
    const int bb = kt & 1;
    const int kb = kt * 64;
    const bool pf = (kt + 1 < nkt);
    short8 ka0, ka1, va0, va1;
    if (pf) {  // issue next tile's global loads; consumed after compute
      const int kb2 = kb + 64;
      ka0 = *(const short8*)(Kp + (kb2 + sr) * 64 + sc * 8);
      ka1 = *(const short8*)(Kp + (kb2 + sr + 32) * 64 + sc * 8);
      va0 = *(const short8*)(Vp + (long)sr * T + kb2 + sc * 8);
      va1 = *(const short8*)(Vp + (long)(sr + 32) * T + kb2 + sc * 8);
    }

    // ---- S^T = K.Q^T from LDS ----
    f32x4 st[4];
#pragma unroll
    for (int g = 0; g < 4; ++g) {
      short8 k0 = Ks[bb][g * 16 + l15][quad ^ rsw];
      short8 k1 = Ks[bb][g * 16 + l15][(4 + quad) ^ rsw];
      f32x4 z = {0.f, 0.f, 0.f, 0.f};
      z = MFMA16(k0, q0, z);
      z = MFMA16(k1, q1, z);
      st[g] = z;
    }
    // ---- online softmax (in-lane over 16 keys, + xor16/xor32) ----
    float a[16];
    float tmax = -INFINITY;
#pragma unroll
    for (int g = 0; g < 4; ++g)
#pragma unroll
      for (int r = 0; r < 4; ++r) {
        int key = kb + g * 16 + quad * 4 + r;
        float v = (key <= myq) ? st[g][r] * cscale : -INFINITY;
        a[g * 4 + r] = v;
        tmax = fmaxf(tmax, v);
      }
    tmax = fmaxf(tmax, __shfl_xor(tmax, 16));
    tmax = fmaxf(tmax, __shfl_xor(tmax, 32));
    const float mnew = fmaxf(m, tmax);
    const float alpha = exp2f(m - mnew);
    m = mnew;
    float rs = 0.f;
#pragma unroll
    for (int g = 0; g < 4; ++g) {
      ushort4 pk;
      float p0 = exp2f(a[g * 4 + 0] - mnew);
      float p1 = exp2f(a[g * 4 + 1] - mnew);
      float p2 = exp2f(a[g * 4 + 2] - mnew);
      float p3 = exp2f(a[g * 4 + 3] - mnew);
      rs += (p0 + p1) + (p2 + p3);
      pk.x = f2bfu(p0); pk.y = f2bfu(p1); pk.z = f2bfu(p2); pk.w = f2bfu(p3);
      *(ushort4*)&Pl[w][l15][g * 16 + quad * 4] = pk;
    }
    rs += __shfl_xor(rs, 16);
    rs += __shfl_xor(rs, 32);
    l = l * alpha + rs;
#pragma unroll
    for (int g = 0; g < 4; ++g)
#pragma unroll
      for (int r = 0; r < 4; ++r) oacc[g][r] *= alpha;
    // ---- O^T += V^T.P^T ----
    short8 pb0 = *(short8*)&Pl[w][l15][quad * 8];
    short8 pb1 = *(short8*)&Pl[w][l15][32 + quad * 8];
#pragma unroll
    for (int g = 0; g < 4; ++g) {
      short8 v0 = Vs[bb][g * 16 + l15][quad ^ rsw];
      short8 v1 = Vs[bb][g * 16 + l15][(4 + quad) ^ rsw];
      oacc[g] = MFMA16(v0, pb0, oacc[g]);
      oacc[g] = MFMA16(v1, pb1, oacc[g]);
    }

    if (pf) {  // write prefetched tile into the other buffer
      const int ob = bb ^ 1;
      Ks[ob][sr][sc ^ (sr & 7)] = ka0;
      Ks[ob][sr + 32][sc ^ (sr & 7)] = ka1;
      Vs[ob][sr][sc ^ (sr & 7)] = va0;
      Vs[ob][sr + 32][sc ^ (sr & 7)] = va1;
    }
    __syncthreads();
  }

  // O^T[d=g*16+quad*4+r][q=l15] -> Y[b*2048+qrow0+l15][h*64 + d]
  const float inv = 1.0f / l;
  unsigned short* Yu = (unsigned short*)Y;
  const long rowoff = ((long)(b * 2048 + qrow0 + l15)) * 1024 + h * 64;
#pragma unroll
  for (int g = 0; g < 4; ++g) {
    ushort4 o;
    o.x = f2bfu(oacc[g][0] * inv);
    o.y = f2bfu(oacc[g][1] * inv);
    o.z = f2bfu(oacc[g][2] * inv);
    o.w = f2bfu(oacc[g][3] * inv);
    *(ushort4*)&Yu[rowoff + g * 16 + quad * 4] = o;
  }
}

extern "C" void kernel_launch(void* const* d_in, const int* in_sizes, int n_in,
                              void* d_out, int out_size, void* d_ws, size_t ws_size,
                              hipStream_t stream) {
  const float* x  = (const float*)d_in[0];   // [4,2048,1024]
  const float* Wa = (const float*)d_in[1];   // [1024,3072]
  const float* ba = (const float*)d_in[2];   // [3072]
  const float* Wp = (const float*)d_in[3];   // [1024,1024]
  const float* bp = (const float*)d_in[4];   // [1024]
  float* out = (float*)d_out;                // [4,2048,1024] fp32

  char* ws = (char*)d_ws;
  __hip_bfloat16* Xb  = (__hip_bfloat16*)(ws);              // [8192,1024]
  __hip_bfloat16* WaT = (__hip_bfloat16*)(ws + 16777216);   // [3072,1024]
  __hip_bfloat16* WpT = (__hip_bfloat16*)(ws + 23068672);   // [1024,1024]
  __hip_bfloat16* Qb  = (__hip_bfloat16*)(ws + 25165824);   // [B,H,T,Dh]
  __hip_bfloat16* Kb  = (__hip_bfloat16*)(ws + 41943040);   // [B,H,T,Dh]
  __hip_bfloat16* Vtb = (__hip_bfloat16*)(ws + 58720256);   // [B,H,Dh,T]
  __hip_bfloat16* Yb  = (__hip_bfloat16*)(ws + 75497472);   // [8192,1024]
  if (ws_size < 92274688) return;

  conv_f32_bf16<<<8192, 256, 0, stream>>>(x, (unsigned short*)Xb, 2097152);
  transpose_bf16<<<dim3(96, 32), dim3(32, 8), 0, stream>>>(Wa, WaT, 1024, 3072);
  transpose_bf16<<<dim3(32, 32), dim3(32, 8), 0, stream>>>(Wp, WpT, 1024, 1024);
  gemm_bt<0><<<dim3(24, 64), 256, 0, stream>>>(Xb, WaT, ba, Qb, Kb, Vtb, 3072, 1024);
  attn_kernel<<<dim3(32, 64), 256, 0, stream>>>(Qb, Kb, Vtb, Yb, 2048);
  gemm_bt<1><<<dim3(8, 64), 256, 0, stream>>>(Yb, WpT, bp, out, nullptr, nullptr, 1024, 1024);
}